// Round 17
// baseline (229.009 us; speedup 1.0000x reference)
//
#include <hip/hip_runtime.h>

typedef __attribute__((ext_vector_type(8))) __bf16 bf16x8;
typedef __attribute__((ext_vector_type(4))) float f32x4;

#define NEG_BIG (-1e30f)

__device__ __forceinline__ unsigned short f2b(float f) {
    unsigned int u = __float_as_uint(f);
    u += 0x7FFFu + ((u >> 16) & 1u);
    return (unsigned short)(u >> 16);
}
__device__ __forceinline__ unsigned cvtpk(float lo, float hi) {
    unsigned r;
    asm("v_cvt_pk_bf16_f32 %0, %1, %2" : "=v"(r) : "v"(lo), "v"(hi));
    return r;
}

typedef const __attribute__((address_space(1))) unsigned int* gas_ptr;
typedef __attribute__((address_space(3))) unsigned int* las_ptr;
__device__ __forceinline__ void gload16(const void* g, void* l) {
    __builtin_amdgcn_global_load_lds((gas_ptr)g, (las_ptr)l, 16, 0, 0);
}

// ---- merged prep: blocks 0..8191 convert x->bf16; 8192..10751 transpose W ----
// Wt rows: 0..2047 = Wq^T, 2048..3071 = Wkv^T, 3072..5119 = Wo^T (K=2048).
__global__ __launch_bounds__(256) void k_prep(
    const float* __restrict__ x, unsigned short* __restrict__ xb,
    const float* __restrict__ Wq, const float* __restrict__ Wkv,
    const float* __restrict__ Wo, unsigned short* __restrict__ Th)
{
    __shared__ float tile[64][65];
    const int blk = blockIdx.x;
    if (blk < 8192) {
        const int i = blk * 256 + threadIdx.x;   // 8192*256 == (2*2048*2048)/4
        float4 v = reinterpret_cast<const float4*>(x)[i];
        ushort4 h;
        h.x = f2b(v.x); h.y = f2b(v.y); h.z = f2b(v.z); h.w = f2b(v.w);
        reinterpret_cast<ushort4*>(xb)[i] = h;
        return;
    }
    const int bx = blk - 8192;
    const int n0g = (bx % 80) * 64, k0 = (bx / 80) * 64;
    const float* W; int N, nloc;
    if (n0g < 2048)      { W = Wq;  N = 2048; nloc = n0g; }
    else if (n0g < 3072) { W = Wkv; N = 1024; nloc = n0g - 2048; }
    else                 { W = Wo;  N = 2048; nloc = n0g - 3072; }
    const int c = threadIdx.x & 63, r0 = threadIdx.x >> 6;
    for (int rr = r0; rr < 64; rr += 4)
        tile[rr][c] = W[(size_t)(k0 + rr) * N + nloc + c];
    __syncthreads();
    for (int rr = r0; rr < 64; rr += 4)
        Th[(size_t)(n0g + rr) * 2048 + k0 + c] = f2b(tile[c][rr]);
}

// ------------- plain bf16 GEMM: C = A * B^T(stored [N][K]) -------------
// BK=64, both-sides XOR swizzle (verified r13). Split epilogue.
__global__ __launch_bounds__(256) void k_gemm(
    const unsigned short* __restrict__ A, const unsigned short* __restrict__ B,
    void* __restrict__ CoutA, int NA, void* __restrict__ CoutB, int NB, int N1,
    const float* __restrict__ bias, int M, int K, int outF32)
{
    __shared__ __align__(16) unsigned short As[128][64];
    __shared__ __align__(16) unsigned short Bs[128][64];

    const int tid  = threadIdx.x;
    const int lane = tid & 63, wid = tid >> 6;
    const int wr = wid >> 1, wc = wid & 1;
    const int lrow = lane & 15, lko = (lane >> 4) << 3;
    const int bm = blockIdx.y, bn = blockIdx.x;

    const int srow = tid >> 3;                       // 0..31
    const int scol = ((tid & 7) ^ (srow & 7)) << 3;  // pre-swizzled k-offset
    const int wbase = wid * 1024;

    const int sw = (lrow & 7) << 3;
    const int c0 = lko ^ sw;
    const int c1 = (32 + lko) ^ sw;

    f32x4 acc[4][4] = {};

    const size_t aoff = (size_t)(bm * 128 + srow) * K + scol;
    const size_t boff = (size_t)(bn * 128 + srow) * K + scol;
    const size_t slab = (size_t)32 * K;

    for (int k0 = 0; k0 < K; k0 += 64) {
        #pragma unroll
        for (int s = 0; s < 4; ++s) {
            gload16(&A[aoff + s * slab + k0], (char*)&As[0][0] + s * 4096 + wbase);
            gload16(&B[boff + s * slab + k0], (char*)&Bs[0][0] + s * 4096 + wbase);
        }
        __syncthreads();

        #pragma unroll
        for (int kk2 = 0; kk2 < 2; ++kk2) {
            const int cc = kk2 ? c1 : c0;
            bf16x8 af[4], bf[4];
            #pragma unroll
            for (int m = 0; m < 4; ++m)
                af[m] = *reinterpret_cast<const bf16x8*>(&As[wr * 64 + m * 16 + lrow][cc]);
            #pragma unroll
            for (int n = 0; n < 4; ++n)
                bf[n] = *reinterpret_cast<const bf16x8*>(&Bs[wc * 64 + n * 16 + lrow][cc]);
            #pragma unroll
            for (int m = 0; m < 4; ++m)
                #pragma unroll
                for (int n = 0; n < 4; ++n)
                    acc[m][n] = __builtin_amdgcn_mfma_f32_16x16x32_bf16(af[m], bf[n], acc[m][n], 0, 0, 0);
        }
        __syncthreads();
    }

    const int rbase = bm * 128 + wr * 64 + ((lane >> 4) << 2);
    const int cbase = bn * 128 + wc * 64 + lrow;
    #pragma unroll
    for (int m = 0; m < 4; ++m)
        #pragma unroll
        for (int n = 0; n < 4; ++n) {
            const int col = cbase + n * 16;
            const float bv = bias ? bias[col] : 0.0f;
            const bool inA = (col < N1);
            const int ccol = inA ? col : (col - N1);
            const int cstr = inA ? NA : NB;
            void* base = inA ? CoutA : CoutB;
            #pragma unroll
            for (int r = 0; r < 4; ++r) {
                const size_t idx = (size_t)(rbase + m * 16 + r) * cstr + ccol;
                const float v = acc[m][n][r] + bv;
                if (outF32) ((float*)base)[idx] = v;
                else        ((unsigned short*)base)[idx] = f2b(v);
            }
        }
}

// ------------- fused causal GQA attention with ALiBi -------------
// r16-verified skeleton (K via global_load_lds DMA, double-buffered;
// V reg-gather-transpose). This round (softmax-section only):
// exp2-domain scores, conditional rescale (skip alpha path when
// __all(mt-mrow<=12), single pe loop), s_setprio around MFMA clusters.
__global__ __launch_bounds__(512, 4) void k_attn(
    const unsigned short* __restrict__ Qb,   // (B*T) x 2048 bf16
    const unsigned short* __restrict__ KVb,  // (B*T) x 1024 bf16 (k | v)
    unsigned short* __restrict__ AO)         // (B*T) x 2048 bf16
{
    __shared__ __align__(16) unsigned short Ksl[2][64][128]; // [buf][key][dim^((key&7)<<3)]
    __shared__ __align__(16) unsigned short Vt[128][72];     // [dim][key], padded
    __shared__ __align__(16) unsigned short Psl[8][16][72];

    const int blk = blockIdx.x;
    const int idx = blk >> 3;          // 0..63
    const int sub = blk & 7;
    const int b   = sub >> 2;
    const int g   = sub & 3;
    const int chunk = (idx < 32) ? (63 - idx) : (idx - 32);
    const int q0  = chunk * 32;        // 32-row chunk base

    const int tid = threadIdx.x;
    const int lane = tid & 63;
    const int w = tid >> 6;            // wave 0..7
    const int h = (w & 3) * 4 + g;     // query head = rep*KVH + g
    const int q0w = q0 + (w >> 2) * 16;  // this wave's 16-row q-tile
    // log2-domain: fold log2(e) into scale and slope
    const float slope2 = exp2f(-0.5f * (float)(h + 1)) * 1.4426950408889634f;
    const float isq2 = 0.12751473460631295f;   // log2(e)/sqrt(128)
    const int lrow = lane & 15;
    const int lko  = (lane >> 4) << 3;
    const int rowg = (lane >> 4) << 2;
    // K DMA staging (512 threads): 2 x gload16 per thread
    const int skey = tid >> 4;                 // 0..31
    const int sd0  = (tid & 15) << 3;          // 0..120
    const int ksrc = sd0 ^ ((skey & 7) << 3);  // pre-swizzled source column
    // V staging (512 threads): 2 key-groups x 8 keys per thread
    const int vdim = tid & 127;                // dim
    const int vkg  = tid >> 7;                 // 0..3

    unsigned short vv[2][8];                   // in-flight V tile (regs)

    auto gloadK = [&](int kb, int buf) {
        const int j0 = kb << 6;
        #pragma unroll
        for (int pp = 0; pp < 2; ++pp) {
            const int key = skey + pp * 32;    // (key&7) == (skey&7)
            gload16(&KVb[(size_t)(b * 2048 + j0 + key) * 1024 + g * 128 + ksrc],
                    (char*)&Ksl[buf][0][0] + pp * 8192 + tid * 16);
        }
    };
    auto ldV = [&](int kb) {
        const int j0 = kb << 6;
        #pragma unroll
        for (int gi = 0; gi < 2; ++gi) {
            const int kgi = gi * 4 + vkg;
            const size_t base = (size_t)(b * 2048 + j0 + kgi * 8) * 1024 + 512 + g * 128 + vdim;
            #pragma unroll
            for (int j = 0; j < 8; ++j)
                vv[gi][j] = KVb[base + (size_t)j * 1024];
        }
    };
    auto wrV = [&]() {
        #pragma unroll
        for (int gi = 0; gi < 2; ++gi) {
            const int kgi = gi * 4 + vkg;
            *reinterpret_cast<uint4*>(&Vt[vdim][kgi * 8]) =
                *reinterpret_cast<const uint4*>(&vv[gi][0]);
        }
    };

    bf16x8 qf[4];
    {
        const size_t qoff = (size_t)(b * 2048 + q0w + lrow) * 2048 + h * 128 + lko;
        #pragma unroll
        for (int kk = 0; kk < 4; ++kk)
            qf[kk] = *reinterpret_cast<const bf16x8*>(&Qb[qoff + kk * 32]);
    }

    f32x4 oacc[8] = {};
    float mrow = NEG_BIG, lsum = 0.f;
    const int nkb = (q0 + 32 + 63) >> 6;       // block-uniform (covers both tiles)
    const int q = q0w + lrow;                  // this lane's q-row

    // prologue: stage tile 0 (K via DMA into buf 0; V via regs)
    gloadK(0, 0);
    ldV(0);
    wrV();
    __syncthreads();                           // drains DMA (vmcnt) + publishes Vt

    int cur = 0;
    for (int kb = 0; kb < nkb; ++kb) {
        const int j0 = kb << 6;
        const bool pre = (kb + 1 < nkb);
        if (pre) { gloadK(kb + 1, cur ^ 1); ldV(kb + 1); }

        // S^T = K Q^T : lane owns q-row q, 16 keys in regs
        f32x4 sa[4] = {};
        __builtin_amdgcn_s_setprio(1);
        #pragma unroll
        for (int c = 0; c < 4; ++c) {
            const int krow = c * 16 + lrow;
            #pragma unroll
            for (int kk = 0; kk < 4; ++kk) {
                bf16x8 kf = *reinterpret_cast<const bf16x8*>(
                    &Ksl[cur][krow][(kk * 32 + lko) ^ ((krow & 7) << 3)]);
                sa[c] = __builtin_amdgcn_mfma_f32_16x16x32_bf16(kf, qf[kk], sa[c], 0, 0, 0);
            }
        }
        __builtin_amdgcn_s_setprio(0);

        // in-lane softmax over 16 values (log2 domain), one q-row per lane
        float pv[4][4];
        float mt = NEG_BIG;
        #pragma unroll
        for (int c = 0; c < 4; ++c)
            #pragma unroll
            for (int r = 0; r < 4; ++r) {
                const int j = j0 + c * 16 + rowg + r;
                const float vsc = (j <= q) ? fmaf(sa[c][r], isq2, slope2 * (float)(j - q)) : NEG_BIG;
                pv[c][r] = vsc;
                mt = fmaxf(mt, vsc);
            }
        mt = fmaxf(mt, __shfl_xor(mt, 16));
        mt = fmaxf(mt, __shfl_xor(mt, 32));

        // conditional rescale: skip alpha path when max grew by <= 12 (log2)
        float mn = mrow;
        if (!__all(mt - mrow <= 12.0f)) {
            mn = fmaxf(mrow, mt);
            const float alpha = exp2f(mrow - mn);
            mrow = mn;
            lsum *= alpha;
            float ar[4];
            #pragma unroll
            for (int r = 0; r < 4; ++r) ar[r] = __shfl(alpha, rowg + r);
            #pragma unroll
            for (int f = 0; f < 8; ++f)
                #pragma unroll
                for (int r = 0; r < 4; ++r)
                    oacc[f][r] *= ar[r];
        }

        float s = 0.f;
        #pragma unroll
        for (int c = 0; c < 4; ++c)
            #pragma unroll
            for (int r = 0; r < 4; ++r) {
                const float pe = exp2f(pv[c][r] - mn);
                pv[c][r] = pe;
                s += pe;
            }
        s += __shfl_xor(s, 16);
        s += __shfl_xor(s, 32);
        lsum += s;

        // P pack (cvt_pk) -> per-wave LDS, b64 writes
        #pragma unroll
        for (int c = 0; c < 4; ++c) {
            uint2 pw;
            pw.x = cvtpk(pv[c][0], pv[c][1]);
            pw.y = cvtpk(pv[c][2], pv[c][3]);
            *reinterpret_cast<uint2*>(&Psl[w][lrow][c * 16 + rowg]) = pw;
        }
        asm volatile("s_waitcnt lgkmcnt(0)" ::: "memory");

        __builtin_amdgcn_s_setprio(1);
        #pragma unroll
        for (int kk2 = 0; kk2 < 2; ++kk2) {
            bf16x8 pf = *reinterpret_cast<const bf16x8*>(&Psl[w][lrow][kk2 * 32 + lko]);
            #pragma unroll
            for (int nb = 0; nb < 8; ++nb) {
                bf16x8 vf = *reinterpret_cast<const bf16x8*>(&Vt[nb * 16 + lrow][kk2 * 32 + lko]);
                oacc[nb] = __builtin_amdgcn_mfma_f32_16x16x32_bf16(pf, vf, oacc[nb], 0, 0, 0);
            }
        }
        __builtin_amdgcn_s_setprio(0);

        __syncthreads();             // all waves done reading Vt/Ksl[cur]
        if (pre) wrV();
        __syncthreads();             // next tile visible (DMA drained too)
        cur ^= 1;
    }

    // epilogue
    float lr[4];
    #pragma unroll
    for (int r = 0; r < 4; ++r) lr[r] = __shfl(lsum, rowg + r);
    #pragma unroll
    for (int nb = 0; nb < 8; ++nb)
        #pragma unroll
        for (int r = 0; r < 4; ++r) {
            const int row = q0w + rowg + r;
            const int col = h * 128 + nb * 16 + lrow;
            const float vo = oacc[nb][r] / lr[r];
            AO[(size_t)(b * 2048 + row) * 2048 + col] = f2b(vo);
        }
}

extern "C" void kernel_launch(void* const* d_in, const int* in_sizes, int n_in,
                              void* d_out, int out_size, void* d_ws, size_t ws_size,
                              hipStream_t stream)
{
    const float* x   = (const float*)d_in[0];  // (2,2048,2048)
    const float* Wq  = (const float*)d_in[1];  // (2048,2048)
    const float* Wkv = (const float*)d_in[2];  // (2048,1024)
    const float* Wo  = (const float*)d_in[3];  // (2048,2048)
    const float* bo  = (const float*)d_in[4];  // (2048,)

    char* ws = (char*)d_ws;
    unsigned short* xb  = (unsigned short*)(ws + (size_t)0);          // 16MB (later AO)
    unsigned short* Wt  = (unsigned short*)(ws + ((size_t)16 << 20)); // 20MB (5120x2048)
    unsigned short* Qb  = (unsigned short*)(ws + ((size_t)36 << 20)); // 16MB
    unsigned short* KVb = (unsigned short*)(ws + ((size_t)52 << 20)); // 8MB
    // total 60MB

    // x -> bf16 AND all weight transposes, one dispatch
    k_prep<<<10752, 256, 0, stream>>>(x, xb, Wq, Wkv, Wo, Wt);

    // fused QKV = x @ [Wq | Wkv]  (4096 x 3072 x 2048), split outputs
    k_gemm<<<dim3(24, 32), 256, 0, stream>>>(xb, Wt, Qb, 2048, KVb, 1024, 2048,
                                             nullptr, 4096, 2048, 0);

    // attention -> AO (reuses x buffer)
    k_attn<<<512, 512, 0, stream>>>(Qb, KVb, xb);

    // out = AO @ Wo + bo   (4096 x 2048 x 2048), f32 out
    k_gemm<<<dim3(16, 32), 256, 0, stream>>>(xb, Wt + (size_t)3072 * 2048, d_out, 2048,
                                             nullptr, 2048, 2048, bo, 4096, 2048, 1);
}

// Round 18
// 228.005 us; speedup vs baseline: 1.0044x; 1.0044x over previous
//
#include <hip/hip_runtime.h>

typedef __attribute__((ext_vector_type(8))) __bf16 bf16x8;
typedef __attribute__((ext_vector_type(4))) float f32x4;

#define NEG_BIG (-1e30f)

__device__ __forceinline__ unsigned short f2b(float f) {
    unsigned int u = __float_as_uint(f);
    u += 0x7FFFu + ((u >> 16) & 1u);
    return (unsigned short)(u >> 16);
}
__device__ __forceinline__ unsigned cvtpk(float lo, float hi) {
    unsigned r;
    asm("v_cvt_pk_bf16_f32 %0, %1, %2" : "=v"(r) : "v"(lo), "v"(hi));
    return r;
}

typedef const __attribute__((address_space(1))) unsigned int* gas_ptr;
typedef __attribute__((address_space(3))) unsigned int* las_ptr;
__device__ __forceinline__ void gload16(const void* g, void* l) {
    __builtin_amdgcn_global_load_lds((gas_ptr)g, (las_ptr)l, 16, 0, 0);
}

// ---- merged prep: blocks 0..8191 convert x->bf16; 8192..10751 transpose W ----
// Wt rows: 0..2047 = Wq^T, 2048..3071 = Wkv^T, 3072..5119 = Wo^T (K=2048).
__global__ __launch_bounds__(256) void k_prep(
    const float* __restrict__ x, unsigned short* __restrict__ xb,
    const float* __restrict__ Wq, const float* __restrict__ Wkv,
    const float* __restrict__ Wo, unsigned short* __restrict__ Th)
{
    __shared__ float tile[64][65];
    const int blk = blockIdx.x;
    if (blk < 8192) {
        const int i = blk * 256 + threadIdx.x;   // 8192*256 == (2*2048*2048)/4
        float4 v = reinterpret_cast<const float4*>(x)[i];
        ushort4 h;
        h.x = f2b(v.x); h.y = f2b(v.y); h.z = f2b(v.z); h.w = f2b(v.w);
        reinterpret_cast<ushort4*>(xb)[i] = h;
        return;
    }
    const int bx = blk - 8192;
    const int n0g = (bx % 80) * 64, k0 = (bx / 80) * 64;
    const float* W; int N, nloc;
    if (n0g < 2048)      { W = Wq;  N = 2048; nloc = n0g; }
    else if (n0g < 3072) { W = Wkv; N = 1024; nloc = n0g - 2048; }
    else                 { W = Wo;  N = 2048; nloc = n0g - 3072; }
    const int c = threadIdx.x & 63, r0 = threadIdx.x >> 6;
    for (int rr = r0; rr < 64; rr += 4)
        tile[rr][c] = W[(size_t)(k0 + rr) * N + nloc + c];
    __syncthreads();
    for (int rr = r0; rr < 64; rr += 4)
        Th[(size_t)(n0g + rr) * 2048 + k0 + c] = f2b(tile[c][rr]);
}

// ------------- plain bf16 GEMM: C = A * B^T(stored [N][K]) -------------
// BK=64, both-sides XOR swizzle (verified r13). Split epilogue.
__global__ __launch_bounds__(256) void k_gemm(
    const unsigned short* __restrict__ A, const unsigned short* __restrict__ B,
    void* __restrict__ CoutA, int NA, void* __restrict__ CoutB, int NB, int N1,
    const float* __restrict__ bias, int M, int K, int outF32)
{
    __shared__ __align__(16) unsigned short As[128][64];
    __shared__ __align__(16) unsigned short Bs[128][64];

    const int tid  = threadIdx.x;
    const int lane = tid & 63, wid = tid >> 6;
    const int wr = wid >> 1, wc = wid & 1;
    const int lrow = lane & 15, lko = (lane >> 4) << 3;
    const int bm = blockIdx.y, bn = blockIdx.x;

    const int srow = tid >> 3;                       // 0..31
    const int scol = ((tid & 7) ^ (srow & 7)) << 3;  // pre-swizzled k-offset
    const int wbase = wid * 1024;

    const int sw = (lrow & 7) << 3;
    const int c0 = lko ^ sw;
    const int c1 = (32 + lko) ^ sw;

    f32x4 acc[4][4] = {};

    const size_t aoff = (size_t)(bm * 128 + srow) * K + scol;
    const size_t boff = (size_t)(bn * 128 + srow) * K + scol;
    const size_t slab = (size_t)32 * K;

    for (int k0 = 0; k0 < K; k0 += 64) {
        #pragma unroll
        for (int s = 0; s < 4; ++s) {
            gload16(&A[aoff + s * slab + k0], (char*)&As[0][0] + s * 4096 + wbase);
            gload16(&B[boff + s * slab + k0], (char*)&Bs[0][0] + s * 4096 + wbase);
        }
        __syncthreads();

        #pragma unroll
        for (int kk2 = 0; kk2 < 2; ++kk2) {
            const int cc = kk2 ? c1 : c0;
            bf16x8 af[4], bf[4];
            #pragma unroll
            for (int m = 0; m < 4; ++m)
                af[m] = *reinterpret_cast<const bf16x8*>(&As[wr * 64 + m * 16 + lrow][cc]);
            #pragma unroll
            for (int n = 0; n < 4; ++n)
                bf[n] = *reinterpret_cast<const bf16x8*>(&Bs[wc * 64 + n * 16 + lrow][cc]);
            #pragma unroll
            for (int m = 0; m < 4; ++m)
                #pragma unroll
                for (int n = 0; n < 4; ++n)
                    acc[m][n] = __builtin_amdgcn_mfma_f32_16x16x32_bf16(af[m], bf[n], acc[m][n], 0, 0, 0);
        }
        __syncthreads();
    }

    const int rbase = bm * 128 + wr * 64 + ((lane >> 4) << 2);
    const int cbase = bn * 128 + wc * 64 + lrow;
    #pragma unroll
    for (int m = 0; m < 4; ++m)
        #pragma unroll
        for (int n = 0; n < 4; ++n) {
            const int col = cbase + n * 16;
            const float bv = bias ? bias[col] : 0.0f;
            const bool inA = (col < N1);
            const int ccol = inA ? col : (col - N1);
            const int cstr = inA ? NA : NB;
            void* base = inA ? CoutA : CoutB;
            #pragma unroll
            for (int r = 0; r < 4; ++r) {
                const size_t idx = (size_t)(rbase + m * 16 + r) * cstr + ccol;
                const float v = acc[m][n][r] + bv;
                if (outF32) ((float*)base)[idx] = v;
                else        ((unsigned short*)base)[idx] = f2b(v);
            }
        }
}

// ------------- fused causal GQA attention with ALiBi -------------
// r16-verified skeleton (K via global_load_lds DMA, double-buffered;
// V reg-gather-transpose). Single delta vs r16: exp2-domain softmax
// (log2e folded into isq2/slope2; exp2f = bare v_exp, saves 17 v_mul/iter).
// No setprio, unconditional rescale (r17 lesson).
__global__ __launch_bounds__(512, 4) void k_attn(
    const unsigned short* __restrict__ Qb,   // (B*T) x 2048 bf16
    const unsigned short* __restrict__ KVb,  // (B*T) x 1024 bf16 (k | v)
    unsigned short* __restrict__ AO)         // (B*T) x 2048 bf16
{
    __shared__ __align__(16) unsigned short Ksl[2][64][128]; // [buf][key][dim^((key&7)<<3)]
    __shared__ __align__(16) unsigned short Vt[128][72];     // [dim][key], padded
    __shared__ __align__(16) unsigned short Psl[8][16][72];

    const int blk = blockIdx.x;
    const int idx = blk >> 3;          // 0..63
    const int sub = blk & 7;
    const int b   = sub >> 2;
    const int g   = sub & 3;
    const int chunk = (idx < 32) ? (63 - idx) : (idx - 32);
    const int q0  = chunk * 32;        // 32-row chunk base

    const int tid = threadIdx.x;
    const int lane = tid & 63;
    const int w = tid >> 6;            // wave 0..7
    const int h = (w & 3) * 4 + g;     // query head = rep*KVH + g
    const int q0w = q0 + (w >> 2) * 16;  // this wave's 16-row q-tile
    // log2-domain constants (single delta vs r16)
    const float slope2 = exp2f(-0.5f * (float)(h + 1)) * 1.4426950408889634f;
    const float isq2 = 0.12751473460631295f;   // log2(e)/sqrt(128)
    const int lrow = lane & 15;
    const int lko  = (lane >> 4) << 3;
    const int rowg = (lane >> 4) << 2;
    // K DMA staging (512 threads): 2 x gload16 per thread
    const int skey = tid >> 4;                 // 0..31
    const int sd0  = (tid & 15) << 3;          // 0..120
    const int ksrc = sd0 ^ ((skey & 7) << 3);  // pre-swizzled source column
    // V staging (512 threads): 2 key-groups x 8 keys per thread
    const int vdim = tid & 127;                // dim
    const int vkg  = tid >> 7;                 // 0..3

    unsigned short vv[2][8];                   // in-flight V tile (regs)

    auto gloadK = [&](int kb, int buf) {
        const int j0 = kb << 6;
        #pragma unroll
        for (int pp = 0; pp < 2; ++pp) {
            const int key = skey + pp * 32;    // (key&7) == (skey&7)
            gload16(&KVb[(size_t)(b * 2048 + j0 + key) * 1024 + g * 128 + ksrc],
                    (char*)&Ksl[buf][0][0] + pp * 8192 + tid * 16);
        }
    };
    auto ldV = [&](int kb) {
        const int j0 = kb << 6;
        #pragma unroll
        for (int gi = 0; gi < 2; ++gi) {
            const int kgi = gi * 4 + vkg;
            const size_t base = (size_t)(b * 2048 + j0 + kgi * 8) * 1024 + 512 + g * 128 + vdim;
            #pragma unroll
            for (int j = 0; j < 8; ++j)
                vv[gi][j] = KVb[base + (size_t)j * 1024];
        }
    };
    auto wrV = [&]() {
        #pragma unroll
        for (int gi = 0; gi < 2; ++gi) {
            const int kgi = gi * 4 + vkg;
            *reinterpret_cast<uint4*>(&Vt[vdim][kgi * 8]) =
                *reinterpret_cast<const uint4*>(&vv[gi][0]);
        }
    };

    bf16x8 qf[4];
    {
        const size_t qoff = (size_t)(b * 2048 + q0w + lrow) * 2048 + h * 128 + lko;
        #pragma unroll
        for (int kk = 0; kk < 4; ++kk)
            qf[kk] = *reinterpret_cast<const bf16x8*>(&Qb[qoff + kk * 32]);
    }

    f32x4 oacc[8] = {};
    float mrow = NEG_BIG, lsum = 0.f;
    const int nkb = (q0 + 32 + 63) >> 6;       // block-uniform (covers both tiles)
    const int q = q0w + lrow;                  // this lane's q-row

    // prologue: stage tile 0 (K via DMA into buf 0; V via regs)
    gloadK(0, 0);
    ldV(0);
    wrV();
    __syncthreads();                           // drains DMA (vmcnt) + publishes Vt

    int cur = 0;
    for (int kb = 0; kb < nkb; ++kb) {
        const int j0 = kb << 6;
        const bool pre = (kb + 1 < nkb);
        if (pre) { gloadK(kb + 1, cur ^ 1); ldV(kb + 1); }

        // S^T = K Q^T : lane owns q-row q, 16 keys in regs
        f32x4 sa[4] = {};
        #pragma unroll
        for (int c = 0; c < 4; ++c) {
            const int krow = c * 16 + lrow;
            #pragma unroll
            for (int kk = 0; kk < 4; ++kk) {
                bf16x8 kf = *reinterpret_cast<const bf16x8*>(
                    &Ksl[cur][krow][(kk * 32 + lko) ^ ((krow & 7) << 3)]);
                sa[c] = __builtin_amdgcn_mfma_f32_16x16x32_bf16(kf, qf[kk], sa[c], 0, 0, 0);
            }
        }

        // in-lane softmax over 16 values (log2 domain), one q-row per lane
        float pv[4][4];
        float mt = NEG_BIG;
        #pragma unroll
        for (int c = 0; c < 4; ++c)
            #pragma unroll
            for (int r = 0; r < 4; ++r) {
                const int j = j0 + c * 16 + rowg + r;
                const float vsc = (j <= q) ? fmaf(sa[c][r], isq2, slope2 * (float)(j - q)) : NEG_BIG;
                pv[c][r] = vsc;
                mt = fmaxf(mt, vsc);
            }
        mt = fmaxf(mt, __shfl_xor(mt, 16));
        mt = fmaxf(mt, __shfl_xor(mt, 32));
        const float mn = fmaxf(mrow, mt);
        const float alpha = exp2f(mrow - mn);
        mrow = mn;
        float s = 0.f;
        #pragma unroll
        for (int c = 0; c < 4; ++c)
            #pragma unroll
            for (int r = 0; r < 4; ++r) {
                const float pe = exp2f(pv[c][r] - mn);
                pv[c][r] = pe;
                s += pe;
            }
        s += __shfl_xor(s, 16);
        s += __shfl_xor(s, 32);
        lsum = lsum * alpha + s;

        // redistribute alpha to PV accumulator rows (q = rowg + r)
        float ar[4];
        #pragma unroll
        for (int r = 0; r < 4; ++r) ar[r] = __shfl(alpha, rowg + r);
        #pragma unroll
        for (int f = 0; f < 8; ++f)
            #pragma unroll
            for (int r = 0; r < 4; ++r)
                oacc[f][r] *= ar[r];

        // P pack (cvt_pk) -> per-wave LDS, b64 writes
        #pragma unroll
        for (int c = 0; c < 4; ++c) {
            uint2 pw;
            pw.x = cvtpk(pv[c][0], pv[c][1]);
            pw.y = cvtpk(pv[c][2], pv[c][3]);
            *reinterpret_cast<uint2*>(&Psl[w][lrow][c * 16 + rowg]) = pw;
        }
        asm volatile("s_waitcnt lgkmcnt(0)" ::: "memory");

        #pragma unroll
        for (int kk2 = 0; kk2 < 2; ++kk2) {
            bf16x8 pf = *reinterpret_cast<const bf16x8*>(&Psl[w][lrow][kk2 * 32 + lko]);
            #pragma unroll
            for (int nb = 0; nb < 8; ++nb) {
                bf16x8 vf = *reinterpret_cast<const bf16x8*>(&Vt[nb * 16 + lrow][kk2 * 32 + lko]);
                oacc[nb] = __builtin_amdgcn_mfma_f32_16x16x32_bf16(pf, vf, oacc[nb], 0, 0, 0);
            }
        }

        __syncthreads();             // all waves done reading Vt/Ksl[cur]
        if (pre) wrV();
        __syncthreads();             // next tile visible (DMA drained too)
        cur ^= 1;
    }

    // epilogue
    float lr[4];
    #pragma unroll
    for (int r = 0; r < 4; ++r) lr[r] = __shfl(lsum, rowg + r);
    #pragma unroll
    for (int nb = 0; nb < 8; ++nb)
        #pragma unroll
        for (int r = 0; r < 4; ++r) {
            const int row = q0w + rowg + r;
            const int col = h * 128 + nb * 16 + lrow;
            const float vo = oacc[nb][r] / lr[r];
            AO[(size_t)(b * 2048 + row) * 2048 + col] = f2b(vo);
        }
}

extern "C" void kernel_launch(void* const* d_in, const int* in_sizes, int n_in,
                              void* d_out, int out_size, void* d_ws, size_t ws_size,
                              hipStream_t stream)
{
    const float* x   = (const float*)d_in[0];  // (2,2048,2048)
    const float* Wq  = (const float*)d_in[1];  // (2048,2048)
    const float* Wkv = (const float*)d_in[2];  // (2048,1024)
    const float* Wo  = (const float*)d_in[3];  // (2048,2048)
    const float* bo  = (const float*)d_in[4];  // (2048,)

    char* ws = (char*)d_ws;
    unsigned short* xb  = (unsigned short*)(ws + (size_t)0);          // 16MB (later AO)
    unsigned short* Wt  = (unsigned short*)(ws + ((size_t)16 << 20)); // 20MB (5120x2048)
    unsigned short* Qb  = (unsigned short*)(ws + ((size_t)36 << 20)); // 16MB
    unsigned short* KVb = (unsigned short*)(ws + ((size_t)52 << 20)); // 8MB
    // total 60MB

    // x -> bf16 AND all weight transposes, one dispatch
    k_prep<<<10752, 256, 0, stream>>>(x, xb, Wq, Wkv, Wo, Wt);

    // fused QKV = x @ [Wq | Wkv]  (4096 x 3072 x 2048), split outputs
    k_gemm<<<dim3(24, 32), 256, 0, stream>>>(xb, Wt, Qb, 2048, KVb, 1024, 2048,
                                             nullptr, 4096, 2048, 0);

    // attention -> AO (reuses x buffer)
    k_attn<<<512, 512, 0, stream>>>(Qb, KVb, xb);

    // out = AO @ Wo + bo   (4096 x 2048 x 2048), f32 out
    k_gemm<<<dim3(16, 32), 256, 0, stream>>>(xb, Wt + (size_t)3072 * 2048, d_out, 2048,
                                             nullptr, 2048, 2048, bo, 4096, 2048, 1);
}

// Round 19
// 221.805 us; speedup vs baseline: 1.0325x; 1.0280x over previous
//
#include <hip/hip_runtime.h>

typedef __attribute__((ext_vector_type(8))) __bf16 bf16x8;
typedef __attribute__((ext_vector_type(4))) float f32x4;

#define NEG_BIG (-1e30f)

__device__ __forceinline__ unsigned short f2b(float f) {
    unsigned int u = __float_as_uint(f);
    u += 0x7FFFu + ((u >> 16) & 1u);
    return (unsigned short)(u >> 16);
}
__device__ __forceinline__ unsigned cvtpk(float lo, float hi) {
    unsigned r;
    asm("v_cvt_pk_bf16_f32 %0, %1, %2" : "=v"(r) : "v"(lo), "v"(hi));
    return r;
}

typedef const __attribute__((address_space(1))) unsigned int* gas_ptr;
typedef __attribute__((address_space(3))) unsigned int* las_ptr;
__device__ __forceinline__ void gload16(const void* g, void* l) {
    __builtin_amdgcn_global_load_lds((gas_ptr)g, (las_ptr)l, 16, 0, 0);
}

// ---- merged prep: blocks 0..8191 convert x->bf16; 8192..10751 transpose W ----
// Wt rows: 0..2047 = Wq^T, 2048..3071 = Wkv^T, 3072..5119 = Wo^T (K=2048).
__global__ __launch_bounds__(256) void k_prep(
    const float* __restrict__ x, unsigned short* __restrict__ xb,
    const float* __restrict__ Wq, const float* __restrict__ Wkv,
    const float* __restrict__ Wo, unsigned short* __restrict__ Th)
{
    __shared__ float tile[64][65];
    const int blk = blockIdx.x;
    if (blk < 8192) {
        const int i = blk * 256 + threadIdx.x;   // 8192*256 == (2*2048*2048)/4
        float4 v = reinterpret_cast<const float4*>(x)[i];
        ushort4 h;
        h.x = f2b(v.x); h.y = f2b(v.y); h.z = f2b(v.z); h.w = f2b(v.w);
        reinterpret_cast<ushort4*>(xb)[i] = h;
        return;
    }
    const int bx = blk - 8192;
    const int n0g = (bx % 80) * 64, k0 = (bx / 80) * 64;
    const float* W; int N, nloc;
    if (n0g < 2048)      { W = Wq;  N = 2048; nloc = n0g; }
    else if (n0g < 3072) { W = Wkv; N = 1024; nloc = n0g - 2048; }
    else                 { W = Wo;  N = 2048; nloc = n0g - 3072; }
    const int c = threadIdx.x & 63, r0 = threadIdx.x >> 6;
    for (int rr = r0; rr < 64; rr += 4)
        tile[rr][c] = W[(size_t)(k0 + rr) * N + nloc + c];
    __syncthreads();
    for (int rr = r0; rr < 64; rr += 4)
        Th[(size_t)(n0g + rr) * 2048 + k0 + c] = f2b(tile[c][rr]);
}

// ------------- plain bf16 GEMM: C = A * B^T(stored [N][K]) -------------
// BK=64, both-sides XOR swizzle (verified r13). Split epilogue.
__global__ __launch_bounds__(256) void k_gemm(
    const unsigned short* __restrict__ A, const unsigned short* __restrict__ B,
    void* __restrict__ CoutA, int NA, void* __restrict__ CoutB, int NB, int N1,
    const float* __restrict__ bias, int M, int K, int outF32)
{
    __shared__ __align__(16) unsigned short As[128][64];
    __shared__ __align__(16) unsigned short Bs[128][64];

    const int tid  = threadIdx.x;
    const int lane = tid & 63, wid = tid >> 6;
    const int wr = wid >> 1, wc = wid & 1;
    const int lrow = lane & 15, lko = (lane >> 4) << 3;
    const int bm = blockIdx.y, bn = blockIdx.x;

    const int srow = tid >> 3;                       // 0..31
    const int scol = ((tid & 7) ^ (srow & 7)) << 3;  // pre-swizzled k-offset
    const int wbase = wid * 1024;

    const int sw = (lrow & 7) << 3;
    const int c0 = lko ^ sw;
    const int c1 = (32 + lko) ^ sw;

    f32x4 acc[4][4] = {};

    const size_t aoff = (size_t)(bm * 128 + srow) * K + scol;
    const size_t boff = (size_t)(bn * 128 + srow) * K + scol;
    const size_t slab = (size_t)32 * K;

    for (int k0 = 0; k0 < K; k0 += 64) {
        #pragma unroll
        for (int s = 0; s < 4; ++s) {
            gload16(&A[aoff + s * slab + k0], (char*)&As[0][0] + s * 4096 + wbase);
            gload16(&B[boff + s * slab + k0], (char*)&Bs[0][0] + s * 4096 + wbase);
        }
        __syncthreads();

        #pragma unroll
        for (int kk2 = 0; kk2 < 2; ++kk2) {
            const int cc = kk2 ? c1 : c0;
            bf16x8 af[4], bf[4];
            #pragma unroll
            for (int m = 0; m < 4; ++m)
                af[m] = *reinterpret_cast<const bf16x8*>(&As[wr * 64 + m * 16 + lrow][cc]);
            #pragma unroll
            for (int n = 0; n < 4; ++n)
                bf[n] = *reinterpret_cast<const bf16x8*>(&Bs[wc * 64 + n * 16 + lrow][cc]);
            #pragma unroll
            for (int m = 0; m < 4; ++m)
                #pragma unroll
                for (int n = 0; n < 4; ++n)
                    acc[m][n] = __builtin_amdgcn_mfma_f32_16x16x32_bf16(af[m], bf[n], acc[m][n], 0, 0, 0);
        }
        __syncthreads();
    }

    const int rbase = bm * 128 + wr * 64 + ((lane >> 4) << 2);
    const int cbase = bn * 128 + wc * 64 + lrow;
    #pragma unroll
    for (int m = 0; m < 4; ++m)
        #pragma unroll
        for (int n = 0; n < 4; ++n) {
            const int col = cbase + n * 16;
            const float bv = bias ? bias[col] : 0.0f;
            const bool inA = (col < N1);
            const int ccol = inA ? col : (col - N1);
            const int cstr = inA ? NA : NB;
            void* base = inA ? CoutA : CoutB;
            #pragma unroll
            for (int r = 0; r < 4; ++r) {
                const size_t idx = (size_t)(rbase + m * 16 + r) * cstr + ccol;
                const float v = acc[m][n][r] + bv;
                if (outF32) ((float*)base)[idx] = v;
                else        ((unsigned short*)base)[idx] = f2b(v);
            }
        }
}

// ------------- fused causal GQA attention with ALiBi -------------
// r16-verified version (97.0 us): K via global_load_lds DMA double-buffered
// (pre-swizzled source col, linear LDS dest); V reg-gather-transpose
// issue-early/write-late. 8 waves: waves 0-3 = q-tile q0, waves 4-7 =
// q-tile q0+16 (same kv head g). __expf softmax (exp2-domain measured
// slower, r18); unconditional rescale; no setprio (r17).
__global__ __launch_bounds__(512, 4) void k_attn(
    const unsigned short* __restrict__ Qb,   // (B*T) x 2048 bf16
    const unsigned short* __restrict__ KVb,  // (B*T) x 1024 bf16 (k | v)
    unsigned short* __restrict__ AO)         // (B*T) x 2048 bf16
{
    __shared__ __align__(16) unsigned short Ksl[2][64][128]; // [buf][key][dim^((key&7)<<3)]
    __shared__ __align__(16) unsigned short Vt[128][72];     // [dim][key], padded
    __shared__ __align__(16) unsigned short Psl[8][16][72];

    const int blk = blockIdx.x;
    const int idx = blk >> 3;          // 0..63
    const int sub = blk & 7;
    const int b   = sub >> 2;
    const int g   = sub & 3;
    const int chunk = (idx < 32) ? (63 - idx) : (idx - 32);
    const int q0  = chunk * 32;        // 32-row chunk base

    const int tid = threadIdx.x;
    const int lane = tid & 63;
    const int w = tid >> 6;            // wave 0..7
    const int h = (w & 3) * 4 + g;     // query head = rep*KVH + g
    const int q0w = q0 + (w >> 2) * 16;  // this wave's 16-row q-tile
    const float slope = exp2f(-0.5f * (float)(h + 1));
    const float isq = 0.088388347648318447f; // 1/sqrt(128)
    const int lrow = lane & 15;
    const int lko  = (lane >> 4) << 3;
    const int rowg = (lane >> 4) << 2;
    // K DMA staging (512 threads): 2 x gload16 per thread
    const int skey = tid >> 4;                 // 0..31
    const int sd0  = (tid & 15) << 3;          // 0..120
    const int ksrc = sd0 ^ ((skey & 7) << 3);  // pre-swizzled source column
    // V staging (512 threads): 2 key-groups x 8 keys per thread
    const int vdim = tid & 127;                // dim
    const int vkg  = tid >> 7;                 // 0..3

    unsigned short vv[2][8];                   // in-flight V tile (regs)

    auto gloadK = [&](int kb, int buf) {
        const int j0 = kb << 6;
        #pragma unroll
        for (int pp = 0; pp < 2; ++pp) {
            const int key = skey + pp * 32;    // (key&7) == (skey&7)
            gload16(&KVb[(size_t)(b * 2048 + j0 + key) * 1024 + g * 128 + ksrc],
                    (char*)&Ksl[buf][0][0] + pp * 8192 + tid * 16);
        }
    };
    auto ldV = [&](int kb) {
        const int j0 = kb << 6;
        #pragma unroll
        for (int gi = 0; gi < 2; ++gi) {
            const int kgi = gi * 4 + vkg;
            const size_t base = (size_t)(b * 2048 + j0 + kgi * 8) * 1024 + 512 + g * 128 + vdim;
            #pragma unroll
            for (int j = 0; j < 8; ++j)
                vv[gi][j] = KVb[base + (size_t)j * 1024];
        }
    };
    auto wrV = [&]() {
        #pragma unroll
        for (int gi = 0; gi < 2; ++gi) {
            const int kgi = gi * 4 + vkg;
            *reinterpret_cast<uint4*>(&Vt[vdim][kgi * 8]) =
                *reinterpret_cast<const uint4*>(&vv[gi][0]);
        }
    };

    bf16x8 qf[4];
    {
        const size_t qoff = (size_t)(b * 2048 + q0w + lrow) * 2048 + h * 128 + lko;
        #pragma unroll
        for (int kk = 0; kk < 4; ++kk)
            qf[kk] = *reinterpret_cast<const bf16x8*>(&Qb[qoff + kk * 32]);
    }

    f32x4 oacc[8] = {};
    float mrow = NEG_BIG, lsum = 0.f;
    const int nkb = (q0 + 32 + 63) >> 6;       // block-uniform (covers both tiles)
    const int q = q0w + lrow;                  // this lane's q-row

    // prologue: stage tile 0 (K via DMA into buf 0; V via regs)
    gloadK(0, 0);
    ldV(0);
    wrV();
    __syncthreads();                           // drains DMA (vmcnt) + publishes Vt

    int cur = 0;
    for (int kb = 0; kb < nkb; ++kb) {
        const int j0 = kb << 6;
        const bool pre = (kb + 1 < nkb);
        if (pre) { gloadK(kb + 1, cur ^ 1); ldV(kb + 1); }

        // S^T = K Q^T : lane owns q-row q, 16 keys in regs
        f32x4 sa[4] = {};
        #pragma unroll
        for (int c = 0; c < 4; ++c) {
            const int krow = c * 16 + lrow;
            #pragma unroll
            for (int kk = 0; kk < 4; ++kk) {
                bf16x8 kf = *reinterpret_cast<const bf16x8*>(
                    &Ksl[cur][krow][(kk * 32 + lko) ^ ((krow & 7) << 3)]);
                sa[c] = __builtin_amdgcn_mfma_f32_16x16x32_bf16(kf, qf[kk], sa[c], 0, 0, 0);
            }
        }

        // in-lane softmax over 16 values (one q-row per lane)
        float pv[4][4];
        float mt = NEG_BIG;
        #pragma unroll
        for (int c = 0; c < 4; ++c)
            #pragma unroll
            for (int r = 0; r < 4; ++r) {
                const int j = j0 + c * 16 + rowg + r;
                const float vsc = (j <= q) ? (sa[c][r] * isq + slope * (float)(j - q)) : NEG_BIG;
                pv[c][r] = vsc;
                mt = fmaxf(mt, vsc);
            }
        mt = fmaxf(mt, __shfl_xor(mt, 16));
        mt = fmaxf(mt, __shfl_xor(mt, 32));
        const float mn = fmaxf(mrow, mt);
        const float alpha = __expf(mrow - mn);
        mrow = mn;
        float s = 0.f;
        #pragma unroll
        for (int c = 0; c < 4; ++c)
            #pragma unroll
            for (int r = 0; r < 4; ++r) {
                const float pe = __expf(pv[c][r] - mn);
                pv[c][r] = pe;
                s += pe;
            }
        s += __shfl_xor(s, 16);
        s += __shfl_xor(s, 32);
        lsum = lsum * alpha + s;

        // redistribute alpha to PV accumulator rows (q = rowg + r)
        float ar[4];
        #pragma unroll
        for (int r = 0; r < 4; ++r) ar[r] = __shfl(alpha, rowg + r);
        #pragma unroll
        for (int f = 0; f < 8; ++f)
            #pragma unroll
            for (int r = 0; r < 4; ++r)
                oacc[f][r] *= ar[r];

        // P pack (cvt_pk) -> per-wave LDS, b64 writes
        #pragma unroll
        for (int c = 0; c < 4; ++c) {
            uint2 pw;
            pw.x = cvtpk(pv[c][0], pv[c][1]);
            pw.y = cvtpk(pv[c][2], pv[c][3]);
            *reinterpret_cast<uint2*>(&Psl[w][lrow][c * 16 + rowg]) = pw;
        }
        asm volatile("s_waitcnt lgkmcnt(0)" ::: "memory");

        #pragma unroll
        for (int kk2 = 0; kk2 < 2; ++kk2) {
            bf16x8 pf = *reinterpret_cast<const bf16x8*>(&Psl[w][lrow][kk2 * 32 + lko]);
            #pragma unroll
            for (int nb = 0; nb < 8; ++nb) {
                bf16x8 vf = *reinterpret_cast<const bf16x8*>(&Vt[nb * 16 + lrow][kk2 * 32 + lko]);
                oacc[nb] = __builtin_amdgcn_mfma_f32_16x16x32_bf16(pf, vf, oacc[nb], 0, 0, 0);
            }
        }

        __syncthreads();             // all waves done reading Vt/Ksl[cur]
        if (pre) wrV();
        __syncthreads();             // next tile visible (DMA drained too)
        cur ^= 1;
    }

    // epilogue
    float lr[4];
    #pragma unroll
    for (int r = 0; r < 4; ++r) lr[r] = __shfl(lsum, rowg + r);
    #pragma unroll
    for (int nb = 0; nb < 8; ++nb)
        #pragma unroll
        for (int r = 0; r < 4; ++r) {
            const int row = q0w + rowg + r;
            const int col = h * 128 + nb * 16 + lrow;
            const float vo = oacc[nb][r] / lr[r];
            AO[(size_t)(b * 2048 + row) * 2048 + col] = f2b(vo);
        }
}

extern "C" void kernel_launch(void* const* d_in, const int* in_sizes, int n_in,
                              void* d_out, int out_size, void* d_ws, size_t ws_size,
                              hipStream_t stream)
{
    const float* x   = (const float*)d_in[0];  // (2,2048,2048)
    const float* Wq  = (const float*)d_in[1];  // (2048,2048)
    const float* Wkv = (const float*)d_in[2];  // (2048,1024)
    const float* Wo  = (const float*)d_in[3];  // (2048,2048)
    const float* bo  = (const float*)d_in[4];  // (2048,)

    char* ws = (char*)d_ws;
    unsigned short* xb  = (unsigned short*)(ws + (size_t)0);          // 16MB (later AO)
    unsigned short* Wt  = (unsigned short*)(ws + ((size_t)16 << 20)); // 20MB (5120x2048)
    unsigned short* Qb  = (unsigned short*)(ws + ((size_t)36 << 20)); // 16MB
    unsigned short* KVb = (unsigned short*)(ws + ((size_t)52 << 20)); // 8MB
    // total 60MB

    // x -> bf16 AND all weight transposes, one dispatch
    k_prep<<<10752, 256, 0, stream>>>(x, xb, Wq, Wkv, Wo, Wt);

    // fused QKV = x @ [Wq | Wkv]  (4096 x 3072 x 2048), split outputs
    k_gemm<<<dim3(24, 32), 256, 0, stream>>>(xb, Wt, Qb, 2048, KVb, 1024, 2048,
                                             nullptr, 4096, 2048, 0);

    // attention -> AO (reuses x buffer)
    k_attn<<<512, 512, 0, stream>>>(Qb, KVb, xb);

    // out = AO @ Wo + bo   (4096 x 2048 x 2048), f32 out
    k_gemm<<<dim3(16, 32), 256, 0, stream>>>(xb, Wt + (size_t)3072 * 2048, d_out, 2048,
                                             nullptr, 2048, 2048, bo, 4096, 2048, 1);
}